// Round 3
// baseline (119.441 us; speedup 1.0000x reference)
//
#include <hip/hip_runtime.h>
#include <hip/hip_bf16.h>
#include <stdint.h>

#define NPAIR 4096
#define N2    8192      // 2N rows
#define DIM   256
#define BK    64
#define NBLOCKS 2080    // 64*65/2 upper-triangle 128x128 blocks
// exp(x/T) = exp2(x * log2(e)/T), T=0.5
#define EXP_SCALE 2.8853900817779268f

typedef short bf16x8 __attribute__((ext_vector_type(8)));
typedef float f32x4  __attribute__((ext_vector_type(4)));

static __device__ __forceinline__ unsigned short f2bf(float f) {
    uint32_t u = __float_as_uint(f);
    uint32_t r = (u + 0x7fffu + ((u >> 16) & 1u)) >> 16;
    return (unsigned short)r;
}

static __device__ __forceinline__ void async_copy16(void* lds, const void* g) {
    __builtin_amdgcn_global_load_lds(
        (const __attribute__((address_space(1))) void*)g,
        (__attribute__((address_space(3))) void*)lds, 16, 0, 0);
}

// ---------------- Kernel A: normalize rows + positive dot + zero rowsum ----
// one wave per pair index i; writes bf16 reps rows i and i+NPAIR,
// stores pdot[i] (NO atomics), zeroes rowsum[2i], rowsum[2i+1], counter.
__global__ __launch_bounds__(64) void normalize_kernel(
    const float* __restrict__ emb_i, const float* __restrict__ emb_j,
    unsigned short* __restrict__ reps, float* __restrict__ pdot,
    float* __restrict__ rowsum, unsigned int* __restrict__ counter) {
    int i = blockIdx.x;
    int l = threadIdx.x;            // 0..63, 4 floats each
    float4 a = ((const float4*)(emb_i + (size_t)i * DIM))[l];
    float4 b = ((const float4*)(emb_j + (size_t)i * DIM))[l];
    float si = a.x*a.x + a.y*a.y + a.z*a.z + a.w*a.w;
    float sj = b.x*b.x + b.y*b.y + b.z*b.z + b.w*b.w;
    float dp = a.x*b.x + a.y*b.y + a.z*b.z + a.w*b.w;
    #pragma unroll
    for (int off = 32; off; off >>= 1) {
        si += __shfl_xor(si, off);
        sj += __shfl_xor(sj, off);
        dp += __shfl_xor(dp, off);
    }
    float ri = 1.0f / fmaxf(sqrtf(si), 1e-12f);
    float rj = 1.0f / fmaxf(sqrtf(sj), 1e-12f);

    ushort4 ua, ub;
    ua.x = f2bf(a.x * ri); ua.y = f2bf(a.y * ri);
    ua.z = f2bf(a.z * ri); ua.w = f2bf(a.w * ri);
    ub.x = f2bf(b.x * rj); ub.y = f2bf(b.y * rj);
    ub.z = f2bf(b.z * rj); ub.w = f2bf(b.w * rj);
    *(ushort4*)(reps + (size_t)i * DIM + l * 4)            = ua;
    *(ushort4*)(reps + (size_t)(i + NPAIR) * DIM + l * 4)  = ub;

    if (l == 0) pdot[i] = dp * ri * rj;
    if (l < 2)  rowsum[2 * i + l] = 0.f;
    if (i == 0 && l == 0) *counter = 0u;
}

// ---------- Kernel B: upper-triangle sim blocks + exp + partial sums -------
// Only blocks (bI <= bJ) of the 64x64 block grid are computed (2080 blocks).
// Every block adds COLUMN partials to rowsum[cols(bJ)]; off-diagonal blocks
// also add ROW partials to rowsum[rows(bI)] (valid since exp(sim/T) is
// symmetric). Diagonal blocks stage one LDS tile (A=B) and mask the diagonal.
// 128x128 tile, 4 waves (2x2), 16x16x32 bf16 MFMA, BK=64, XOR-swizzled LDS
// (both-sides: pre-swizzled global source + swizzled ds_read; rule #21).
// The LAST block to finish also performs the finalize reduction.
__global__ __launch_bounds__(256) void simexp_kernel(
    const unsigned short* __restrict__ reps, float* __restrict__ rowsum,
    const float* __restrict__ pdot, unsigned int* __restrict__ counter,
    float* __restrict__ out) {
    __shared__ unsigned short As[128 * BK];
    __shared__ unsigned short Bs[128 * BK];

    int t = threadIdx.x;
    int l = t & 63;
    int w = t >> 6;
    int wr = w >> 1, wc = w & 1;

    // triangle decode: idx = bJ*(bJ+1)/2 + bI, bI <= bJ
    int idx = blockIdx.x;
    int bJ = (int)((sqrtf(8.0f * (float)idx + 1.0f) - 1.0f) * 0.5f);
    while ((bJ + 1) * (bJ + 2) / 2 <= idx) ++bJ;
    while (bJ * (bJ + 1) / 2 > idx) --bJ;
    int bI = idx - bJ * (bJ + 1) / 2;
    int brow = bI * 128;
    int bcol = bJ * 128;
    bool diag = (bI == bJ);

    f32x4 acc[4][4];
    #pragma unroll
    for (int mi = 0; mi < 4; ++mi)
        #pragma unroll
        for (int ni = 0; ni < 4; ++ni)
            acc[mi][ni] = (f32x4){0.f, 0.f, 0.f, 0.f};

    int frow = l & 15;
    int k16  = l >> 4;          // 0..3
    const unsigned short* Bbase = diag ? As : Bs;

    for (int kt = 0; kt < DIM; kt += BK) {
        __syncthreads();   // previous iter's ds_reads complete before overwrite
        #pragma unroll
        for (int p = 0; p < 4; ++p) {
            int f16  = t + p * 256;       // 16B-chunk index, 0..1023
            int r    = f16 >> 3;          // tile row (8 chunks per 128B row)
            int slot = f16 & 7;           // 16B slot within row
            int gk   = (slot ^ (r & 7)) * 8;   // pre-swizzled global k-chunk
            async_copy16(&As[f16 * 8], reps + (size_t)(brow + r) * DIM + kt + gk);
            if (!diag)
                async_copy16(&Bs[f16 * 8], reps + (size_t)(bcol + r) * DIM + kt + gk);
        }
        asm volatile("s_waitcnt vmcnt(0)" ::: "memory");
        __syncthreads();

        #pragma unroll
        for (int kk = 0; kk < 2; ++kk) {
            bf16x8 afr[4], bfr[4];
            #pragma unroll
            for (int ni = 0; ni < 4; ++ni) {
                int r    = wc * 64 + ni * 16 + frow;
                int slot = (kk * 4 + k16) ^ (r & 7);
                bfr[ni] = *(const bf16x8*)&Bbase[r * BK + slot * 8];
            }
            #pragma unroll
            for (int mi = 0; mi < 4; ++mi) {
                int r    = wr * 64 + mi * 16 + frow;
                int slot = (kk * 4 + k16) ^ (r & 7);
                afr[mi] = *(const bf16x8*)&As[r * BK + slot * 8];
            }
            #pragma unroll
            for (int mi = 0; mi < 4; ++mi)
                #pragma unroll
                for (int ni = 0; ni < 4; ++ni)
                    acc[mi][ni] = __builtin_amdgcn_mfma_f32_16x16x32_bf16(
                        afr[mi], bfr[ni], acc[mi][ni], 0, 0, 0);
        }
    }

    // Epilogue. C/D layout: col = lane&15, row = (lane>>4)*4 + j  [m89/m91]
    // per-lane: csum[ni] = column partials, rpart[mi*4+j] = row partials.
    int rbase = brow + wr * 64 + k16 * 4;
    int cb    = bcol + wc * 64 + frow;
    float csum[4]   = {0.f, 0.f, 0.f, 0.f};
    float rpart[16];
    #pragma unroll
    for (int mi = 0; mi < 4; ++mi) {
        #pragma unroll
        for (int j = 0; j < 4; ++j) {
            int grow = rbase + mi * 16 + j;
            float rp = 0.f;
            #pragma unroll
            for (int ni = 0; ni < 4; ++ni) {
                float e = exp2f(acc[mi][ni][j] * EXP_SCALE);
                e = (grow == cb + ni * 16) ? 0.f : e;   // main diagonal only
                csum[ni] += e;
                rp += e;
            }
            rpart[mi * 4 + j] = rp;
        }
    }
    // column totals: reduce over k16 groups (xor 16,32); 1 atomic per lane
    #pragma unroll
    for (int ni = 0; ni < 4; ++ni) {
        csum[ni] += __shfl_xor(csum[ni], 16);
        csum[ni] += __shfl_xor(csum[ni], 32);
    }
    float cv = csum[0];
    #pragma unroll
    for (int v = 1; v < 4; ++v) cv = (k16 == v) ? csum[v] : cv;  // static idx
    atomicAdd(&rowsum[bcol + wc * 64 + k16 * 16 + frow], cv);

    if (!diag) {
        // row totals: reduce over frow bits (xor 1,2,4,8); 1 atomic per lane
        #pragma unroll
        for (int v = 0; v < 16; ++v) {
            rpart[v] += __shfl_xor(rpart[v], 1);
            rpart[v] += __shfl_xor(rpart[v], 2);
            rpart[v] += __shfl_xor(rpart[v], 4);
            rpart[v] += __shfl_xor(rpart[v], 8);
        }
        float rv = rpart[0];
        #pragma unroll
        for (int v = 1; v < 16; ++v) rv = (frow == v) ? rpart[v] : rv;
        int grow = brow + wr * 64 + k16 * 4 + (frow >> 2) * 16 + (frow & 3);
        atomicAdd(&rowsum[grow], rv);
    }

    // ---- fused finalize: last block to arrive reduces rowsum + pdot ----
    __shared__ int lastFlag;
    __shared__ float reds[4], redp[4];
    if (t == 0) {
        __threadfence();                       // release: my atomics visible
        unsigned prev = atomicAdd(counter, 1u);
        lastFlag = (prev == (unsigned)(NBLOCKS - 1));
        __threadfence();                       // acquire side
    }
    __syncthreads();
    if (!lastFlag) return;

    float s = 0.f, p = 0.f;
    for (int r = t; r < N2; r += 256) {
        float v = __hip_atomic_load(&rowsum[r], __ATOMIC_RELAXED,
                                    __HIP_MEMORY_SCOPE_AGENT);
        s += log2f(v) * 0.6931471805599453f;
    }
    for (int r = t; r < NPAIR; r += 256) p += pdot[r];
    #pragma unroll
    for (int off = 32; off; off >>= 1) {
        s += __shfl_xor(s, off);
        p += __shfl_xor(p, off);
    }
    if (l == 0) { reds[w] = s; redp[w] = p; }
    __syncthreads();
    if (t == 0) {
        float S = reds[0] + reds[1] + reds[2] + reds[3];
        float P = redp[0] + redp[1] + redp[2] + redp[3];
        // loss = (sum log D - (2/T)*2*sum(dp)) / 2N ; (2/T)*2 folded: 4*P
        out[0] = (S - 4.0f * P) / (float)N2;
    }
}

extern "C" void kernel_launch(void* const* d_in, const int* in_sizes, int n_in,
                              void* d_out, int out_size, void* d_ws, size_t ws_size,
                              hipStream_t stream) {
    const float* emb_i = (const float*)d_in[0];
    const float* emb_j = (const float*)d_in[1];
    float* out = (float*)d_out;

    char* ws = (char*)d_ws;
    float*          rowsum  = (float*)ws;                  // 8192 * 4 B
    float*          pdot    = (float*)(ws + 32768);        // 4096 * 4 B
    unsigned int*   counter = (unsigned int*)(ws + 49152); // 4 B
    unsigned short* reps    = (unsigned short*)(ws + 65536); // 8192*256*2 B

    normalize_kernel<<<NPAIR, 64, 0, stream>>>(emb_i, emb_j, reps, pdot,
                                               rowsum, counter);

    simexp_kernel<<<NBLOCKS, 256, 0, stream>>>(reps, rowsum, pdot, counter, out);
}

// Round 4
// 59.125 us; speedup vs baseline: 2.0201x; 2.0201x over previous
//
#include <hip/hip_runtime.h>
#include <hip/hip_bf16.h>
#include <stdint.h>

#define NPAIR 4096
#define N2    8192      // 2N rows
#define DIM   256
#define BK    64
#define NBLOCKS 2080    // 64*65/2 upper-triangle 128x128 blocks
// exp(x/T) = exp2(x * log2(e)/T), T=0.5
#define EXP_SCALE 2.8853900817779268f

typedef short bf16x8 __attribute__((ext_vector_type(8)));
typedef float f32x4  __attribute__((ext_vector_type(4)));

static __device__ __forceinline__ unsigned short f2bf(float f) {
    uint32_t u = __float_as_uint(f);
    uint32_t r = (u + 0x7fffu + ((u >> 16) & 1u)) >> 16;
    return (unsigned short)r;
}

static __device__ __forceinline__ void async_copy16(void* lds, const void* g) {
    __builtin_amdgcn_global_load_lds(
        (const __attribute__((address_space(1))) void*)g,
        (__attribute__((address_space(3))) void*)lds, 16, 0, 0);
}

// ---------------- Kernel A: normalize rows + positive dot + zero rowsum ----
// 4 waves per block, one wave per pair; writes bf16 reps rows i and i+NPAIR,
// stores pdot[i] (no atomics), zeroes rowsum[2i], rowsum[2i+1].
__global__ __launch_bounds__(256) void normalize_kernel(
    const float* __restrict__ emb_i, const float* __restrict__ emb_j,
    unsigned short* __restrict__ reps, float* __restrict__ pdot,
    float* __restrict__ rowsum) {
    int i = blockIdx.x * 4 + (threadIdx.x >> 6);
    int l = threadIdx.x & 63;       // 0..63, 4 floats each
    float4 a = ((const float4*)(emb_i + (size_t)i * DIM))[l];
    float4 b = ((const float4*)(emb_j + (size_t)i * DIM))[l];
    float si = a.x*a.x + a.y*a.y + a.z*a.z + a.w*a.w;
    float sj = b.x*b.x + b.y*b.y + b.z*b.z + b.w*b.w;
    float dp = a.x*b.x + a.y*b.y + a.z*b.z + a.w*b.w;
    #pragma unroll
    for (int off = 32; off; off >>= 1) {
        si += __shfl_xor(si, off);
        sj += __shfl_xor(sj, off);
        dp += __shfl_xor(dp, off);
    }
    float ri = 1.0f / fmaxf(sqrtf(si), 1e-12f);
    float rj = 1.0f / fmaxf(sqrtf(sj), 1e-12f);

    ushort4 ua, ub;
    ua.x = f2bf(a.x * ri); ua.y = f2bf(a.y * ri);
    ua.z = f2bf(a.z * ri); ua.w = f2bf(a.w * ri);
    ub.x = f2bf(b.x * rj); ub.y = f2bf(b.y * rj);
    ub.z = f2bf(b.z * rj); ub.w = f2bf(b.w * rj);
    *(ushort4*)(reps + (size_t)i * DIM + l * 4)            = ua;
    *(ushort4*)(reps + (size_t)(i + NPAIR) * DIM + l * 4)  = ub;

    if (l == 0) pdot[i] = dp * ri * rj;
    if (l < 2)  rowsum[2 * i + l] = 0.f;
}

// ---------- Kernel B: upper-triangle sim blocks + exp + partial sums -------
// Only blocks (bI <= bJ) of the 64x64 block grid (2080 blocks). Every block
// adds COLUMN partials to rowsum[cols(bJ)]; off-diagonal blocks also add ROW
// partials to rowsum[rows(bI)] (valid: exp(sim/T) is symmetric). Diagonal
// blocks stage Bs from the same global rows as As (L2-hit) so the hot loop
// is branch-free with compile-time LDS bases; the main diagonal is masked.
// 128x128 tile, 4 waves (2x2), 16x16x32 bf16 MFMA, BK=64, XOR-swizzled LDS
// (both-sides: pre-swizzled global source + swizzled ds_read; rule #21).
__global__ __launch_bounds__(256) void simexp_kernel(
    const unsigned short* __restrict__ reps, float* __restrict__ rowsum) {
    __shared__ unsigned short As[128 * BK];
    __shared__ unsigned short Bs[128 * BK];

    int t = threadIdx.x;
    int l = t & 63;
    int w = t >> 6;
    int wr = w >> 1, wc = w & 1;

    // triangle decode: idx = bJ*(bJ+1)/2 + bI, bI <= bJ
    int idx = blockIdx.x;
    int bJ = (int)((sqrtf(8.0f * (float)idx + 1.0f) - 1.0f) * 0.5f);
    while ((bJ + 1) * (bJ + 2) / 2 <= idx) ++bJ;
    while (bJ * (bJ + 1) / 2 > idx) --bJ;
    int bI = idx - bJ * (bJ + 1) / 2;
    int brow = bI * 128;
    int bcol = bJ * 128;
    bool diag = (bI == bJ);

    f32x4 acc[4][4];
    #pragma unroll
    for (int mi = 0; mi < 4; ++mi)
        #pragma unroll
        for (int ni = 0; ni < 4; ++ni)
            acc[mi][ni] = (f32x4){0.f, 0.f, 0.f, 0.f};

    int frow = l & 15;
    int k16  = l >> 4;          // 0..3

    for (int kt = 0; kt < DIM; kt += BK) {
        __syncthreads();   // previous iter's ds_reads complete before overwrite
        #pragma unroll
        for (int p = 0; p < 4; ++p) {
            int f16  = t + p * 256;       // 16B-chunk index, 0..1023
            int r    = f16 >> 3;          // tile row (8 chunks per 128B row)
            int slot = f16 & 7;           // 16B slot within row
            int gk   = (slot ^ (r & 7)) * 8;   // pre-swizzled global k-chunk
            async_copy16(&As[f16 * 8], reps + (size_t)(brow + r) * DIM + kt + gk);
            async_copy16(&Bs[f16 * 8], reps + (size_t)(bcol + r) * DIM + kt + gk);
        }
        asm volatile("s_waitcnt vmcnt(0)" ::: "memory");
        __syncthreads();

        #pragma unroll
        for (int kk = 0; kk < 2; ++kk) {
            bf16x8 afr[4], bfr[4];
            #pragma unroll
            for (int ni = 0; ni < 4; ++ni) {
                int r    = wc * 64 + ni * 16 + frow;
                int slot = (kk * 4 + k16) ^ (r & 7);
                bfr[ni] = *(const bf16x8*)&Bs[r * BK + slot * 8];
            }
            #pragma unroll
            for (int mi = 0; mi < 4; ++mi) {
                int r    = wr * 64 + mi * 16 + frow;
                int slot = (kk * 4 + k16) ^ (r & 7);
                afr[mi] = *(const bf16x8*)&As[r * BK + slot * 8];
            }
            #pragma unroll
            for (int mi = 0; mi < 4; ++mi)
                #pragma unroll
                for (int ni = 0; ni < 4; ++ni)
                    acc[mi][ni] = __builtin_amdgcn_mfma_f32_16x16x32_bf16(
                        afr[mi], bfr[ni], acc[mi][ni], 0, 0, 0);
        }
    }

    // Epilogue. C/D layout: col = lane&15, row = (lane>>4)*4 + j  [m89/m91]
    // csum[ni]: column partials (reduced over k16 groups).
    // rv: this lane's row total; row partial rp(mi,j) is shuffle-reduced
    // over the 16 frow lanes immediately (keeps live registers low) and
    // kept by the lane with frow == mi*4+j.
    int rbase = brow + wr * 64 + k16 * 4;
    int cb    = bcol + wc * 64 + frow;
    float csum[4] = {0.f, 0.f, 0.f, 0.f};
    float rv = 0.f;
    #pragma unroll
    for (int mi = 0; mi < 4; ++mi) {
        #pragma unroll
        for (int j = 0; j < 4; ++j) {
            int grow = rbase + mi * 16 + j;
            float rp = 0.f;
            #pragma unroll
            for (int ni = 0; ni < 4; ++ni) {
                float e = exp2f(acc[mi][ni][j] * EXP_SCALE);
                e = (grow == cb + ni * 16) ? 0.f : e;   // main diagonal only
                csum[ni] += e;
                rp += e;
            }
            rp += __shfl_xor(rp, 1);
            rp += __shfl_xor(rp, 2);
            rp += __shfl_xor(rp, 4);
            rp += __shfl_xor(rp, 8);
            rv = (frow == mi * 4 + j) ? rp : rv;
        }
    }
    // column totals: reduce over k16 groups; 1 atomic per lane
    #pragma unroll
    for (int ni = 0; ni < 4; ++ni) {
        csum[ni] += __shfl_xor(csum[ni], 16);
        csum[ni] += __shfl_xor(csum[ni], 32);
    }
    float cv = csum[0];
    #pragma unroll
    for (int v = 1; v < 4; ++v) cv = (k16 == v) ? csum[v] : cv;  // static idx
    atomicAdd(&rowsum[bcol + wc * 64 + k16 * 16 + frow], cv);

    if (!diag) {
        int grow = brow + wr * 64 + k16 * 4 + (frow >> 2) * 16 + (frow & 3);
        atomicAdd(&rowsum[grow], rv);
    }
}

// ---------------- Kernel C: finalize ----------------
__global__ __launch_bounds__(256) void finalize_kernel(
    const float* __restrict__ rowsum, const float* __restrict__ pdot,
    float* __restrict__ out) {
    int t = threadIdx.x;
    float s = 0.f, p = 0.f;
    for (int r = t; r < N2; r += 256)    s += logf(rowsum[r]);
    for (int r = t; r < NPAIR; r += 256) p += pdot[r];
    #pragma unroll
    for (int off = 32; off; off >>= 1) {
        s += __shfl_xor(s, off);
        p += __shfl_xor(p, off);
    }
    __shared__ float reds[4], redp[4];
    if ((t & 63) == 0) { reds[t >> 6] = s; redp[t >> 6] = p; }
    __syncthreads();
    if (t == 0) {
        float S = reds[0] + reds[1] + reds[2] + reds[3];
        float P = redp[0] + redp[1] + redp[2] + redp[3];
        // loss = (sum log D - (2/T)*2*sum(dp)) / 2N ; (2/T)*2 folded: 4*P
        out[0] = (S - 4.0f * P) / (float)N2;
    }
}

extern "C" void kernel_launch(void* const* d_in, const int* in_sizes, int n_in,
                              void* d_out, int out_size, void* d_ws, size_t ws_size,
                              hipStream_t stream) {
    const float* emb_i = (const float*)d_in[0];
    const float* emb_j = (const float*)d_in[1];
    float* out = (float*)d_out;

    char* ws = (char*)d_ws;
    float*          rowsum = (float*)ws;                    // 8192 * 4 B
    float*          pdot   = (float*)(ws + 32768);          // 4096 * 4 B
    unsigned short* reps   = (unsigned short*)(ws + 65536); // 8192*256*2 B

    normalize_kernel<<<NPAIR / 4, 256, 0, stream>>>(emb_i, emb_j, reps, pdot,
                                                    rowsum);

    simexp_kernel<<<NBLOCKS, 256, 0, stream>>>(reps, rowsum);

    finalize_kernel<<<1, 256, 0, stream>>>(rowsum, pdot, out);
}

// Round 5
// 55.122 us; speedup vs baseline: 2.1669x; 1.0726x over previous
//
#include <hip/hip_runtime.h>
#include <hip/hip_bf16.h>
#include <stdint.h>

#define NPAIR 4096
#define N2    8192      // 2N rows
#define DIM   256
#define BK    64
#define NK    (DIM / BK)   // 4 K-steps
#define NBLOCKS 2080       // 64*65/2 upper-triangle 128x128 blocks
// exp(x/T) = exp2(x * log2(e)/T), T=0.5
#define EXP_SCALE 2.8853900817779268f

typedef short bf16x8 __attribute__((ext_vector_type(8)));
typedef float f32x4  __attribute__((ext_vector_type(4)));

static __device__ __forceinline__ unsigned short f2bf(float f) {
    uint32_t u = __float_as_uint(f);
    uint32_t r = (u + 0x7fffu + ((u >> 16) & 1u)) >> 16;
    return (unsigned short)r;
}

static __device__ __forceinline__ void async_copy16(void* lds, const void* g) {
    __builtin_amdgcn_global_load_lds(
        (const __attribute__((address_space(1))) void*)g,
        (__attribute__((address_space(3))) void*)lds, 16, 0, 0);
}

// ---------------- Kernel A: normalize rows + positive dot + zero rowsum ----
// 4 waves per block, one wave per pair; writes bf16 reps rows i and i+NPAIR,
// stores pdot[i] (no atomics), zeroes rowsum[2i], rowsum[2i+1].
__global__ __launch_bounds__(256) void normalize_kernel(
    const float* __restrict__ emb_i, const float* __restrict__ emb_j,
    unsigned short* __restrict__ reps, float* __restrict__ pdot,
    float* __restrict__ rowsum) {
    int i = blockIdx.x * 4 + (threadIdx.x >> 6);
    int l = threadIdx.x & 63;       // 0..63, 4 floats each
    float4 a = ((const float4*)(emb_i + (size_t)i * DIM))[l];
    float4 b = ((const float4*)(emb_j + (size_t)i * DIM))[l];
    float si = a.x*a.x + a.y*a.y + a.z*a.z + a.w*a.w;
    float sj = b.x*b.x + b.y*b.y + b.z*b.z + b.w*b.w;
    float dp = a.x*b.x + a.y*b.y + a.z*b.z + a.w*b.w;
    #pragma unroll
    for (int off = 32; off; off >>= 1) {
        si += __shfl_xor(si, off);
        sj += __shfl_xor(sj, off);
        dp += __shfl_xor(dp, off);
    }
    float ri = 1.0f / fmaxf(sqrtf(si), 1e-12f);
    float rj = 1.0f / fmaxf(sqrtf(sj), 1e-12f);

    ushort4 ua, ub;
    ua.x = f2bf(a.x * ri); ua.y = f2bf(a.y * ri);
    ua.z = f2bf(a.z * ri); ua.w = f2bf(a.w * ri);
    ub.x = f2bf(b.x * rj); ub.y = f2bf(b.y * rj);
    ub.z = f2bf(b.z * rj); ub.w = f2bf(b.w * rj);
    *(ushort4*)(reps + (size_t)i * DIM + l * 4)            = ua;
    *(ushort4*)(reps + (size_t)(i + NPAIR) * DIM + l * 4)  = ub;

    if (l == 0) pdot[i] = dp * ri * rj;
    if (l < 2)  rowsum[2 * i + l] = 0.f;
}

// ---------- Kernel B: upper-triangle sim blocks + exp + partial sums -------
// Only blocks (bI <= bJ) of the 64x64 block grid (2080 blocks). Every block
// adds COLUMN partials to rowsum[cols(bJ)]; off-diagonal blocks also add ROW
// partials to rowsum[rows(bI)] (valid: exp(sim/T) is symmetric). Diagonal
// blocks stage Bs from the same global rows as As (L2-hit, branch-free).
// 128x128 tile, 4 waves (2x2), 16x16x32 bf16 MFMA, BK=64, XOR-swizzled LDS
// (both-sides: pre-swizzled global source + swizzled ds_read; rule #21).
// K-loop is T3 "minimum 2-phase": double-buffered LDS, STAGE(kt+1) issued
// BEFORE compute(kt), single vmcnt(0)+barrier per K-step AFTER compute, so
// global->LDS latency hides under ds_read+MFMA.
__global__ __launch_bounds__(256) void simexp_kernel(
    const unsigned short* __restrict__ reps, float* __restrict__ rowsum) {
    __shared__ unsigned short As[2][128 * BK];
    __shared__ unsigned short Bs[2][128 * BK];

    int t = threadIdx.x;
    int l = t & 63;
    int w = t >> 6;
    int wr = w >> 1, wc = w & 1;

    // triangle decode: idx = bJ*(bJ+1)/2 + bI, bI <= bJ
    int idx = blockIdx.x;
    int bJ = (int)((sqrtf(8.0f * (float)idx + 1.0f) - 1.0f) * 0.5f);
    while ((bJ + 1) * (bJ + 2) / 2 <= idx) ++bJ;
    while (bJ * (bJ + 1) / 2 > idx) --bJ;
    int bI = idx - bJ * (bJ + 1) / 2;
    int brow = bI * 128;
    int bcol = bJ * 128;
    bool diag = (bI == bJ);

    f32x4 acc[4][4];
    #pragma unroll
    for (int mi = 0; mi < 4; ++mi)
        #pragma unroll
        for (int ni = 0; ni < 4; ++ni)
            acc[mi][ni] = (f32x4){0.f, 0.f, 0.f, 0.f};

    int frow = l & 15;
    int k16  = l >> 4;          // 0..3

    // staging addresses (per-thread constants across K-steps)
    int f16r  = t >> 3;                 // tile row for my 16B chunk
    int slot0 = t & 7;                  // slot within 128B row
    int gk0   = (slot0 ^ (f16r & 7)) * 8;   // pre-swizzled k-chunk (elements)

    #define STAGE(buf, kt)                                                     \
        _Pragma("unroll")                                                      \
        for (int p = 0; p < 4; ++p) {                                          \
            int r = f16r + p * 32;                                             \
            async_copy16(&As[buf][(t + p * 256) * 8],                          \
                         reps + (size_t)(brow + r) * DIM + (kt) * BK + gk0);   \
            async_copy16(&Bs[buf][(t + p * 256) * 8],                          \
                         reps + (size_t)(bcol + r) * DIM + (kt) * BK + gk0);   \
        }

    STAGE(0, 0);
    asm volatile("s_waitcnt vmcnt(0)" ::: "memory");
    __syncthreads();

    #pragma unroll
    for (int kt = 0; kt < NK; ++kt) {
        const int cur = kt & 1;
        if (kt < NK - 1) { STAGE(cur ^ 1, kt + 1); }   // prefetch next K-tile

        #pragma unroll
        for (int kk = 0; kk < 2; ++kk) {
            bf16x8 afr[4], bfr[4];
            #pragma unroll
            for (int ni = 0; ni < 4; ++ni) {
                int r    = wc * 64 + ni * 16 + frow;
                int slot = (kk * 4 + k16) ^ (r & 7);
                bfr[ni] = *(const bf16x8*)&Bs[cur][r * BK + slot * 8];
            }
            #pragma unroll
            for (int mi = 0; mi < 4; ++mi) {
                int r    = wr * 64 + mi * 16 + frow;
                int slot = (kk * 4 + k16) ^ (r & 7);
                afr[mi] = *(const bf16x8*)&As[cur][r * BK + slot * 8];
            }
            #pragma unroll
            for (int mi = 0; mi < 4; ++mi)
                #pragma unroll
                for (int ni = 0; ni < 4; ++ni)
                    acc[mi][ni] = __builtin_amdgcn_mfma_f32_16x16x32_bf16(
                        afr[mi], bfr[ni], acc[mi][ni], 0, 0, 0);
        }

        if (kt < NK - 1) {
            asm volatile("s_waitcnt vmcnt(0)" ::: "memory");  // next tile landed
            __syncthreads();   // also separates reads(cur) from next STAGE(cur)
        }
    }
    #undef STAGE

    // Epilogue. C/D layout: col = lane&15, row = (lane>>4)*4 + j  [m89/m91]
    // csum[ni]: column partials (reduced over k16 groups).
    // rv: this lane's row total; row partial rp(mi,j) is shuffle-reduced
    // over the 16 frow lanes immediately and kept by lane frow == mi*4+j.
    int rbase = brow + wr * 64 + k16 * 4;
    int cb    = bcol + wc * 64 + frow;
    float csum[4] = {0.f, 0.f, 0.f, 0.f};
    float rv = 0.f;
    #pragma unroll
    for (int mi = 0; mi < 4; ++mi) {
        #pragma unroll
        for (int j = 0; j < 4; ++j) {
            int grow = rbase + mi * 16 + j;
            float rp = 0.f;
            #pragma unroll
            for (int ni = 0; ni < 4; ++ni) {
                float e = exp2f(acc[mi][ni][j] * EXP_SCALE);
                e = (grow == cb + ni * 16) ? 0.f : e;   // main diagonal only
                csum[ni] += e;
                rp += e;
            }
            rp += __shfl_xor(rp, 1);
            rp += __shfl_xor(rp, 2);
            rp += __shfl_xor(rp, 4);
            rp += __shfl_xor(rp, 8);
            rv = (frow == mi * 4 + j) ? rp : rv;
        }
    }
    // column totals: reduce over k16 groups; 1 atomic per lane
    #pragma unroll
    for (int ni = 0; ni < 4; ++ni) {
        csum[ni] += __shfl_xor(csum[ni], 16);
        csum[ni] += __shfl_xor(csum[ni], 32);
    }
    float cv = csum[0];
    #pragma unroll
    for (int v = 1; v < 4; ++v) cv = (k16 == v) ? csum[v] : cv;  // static idx
    atomicAdd(&rowsum[bcol + wc * 64 + k16 * 16 + frow], cv);

    if (!diag) {
        int grow = brow + wr * 64 + k16 * 4 + (frow >> 2) * 16 + (frow & 3);
        atomicAdd(&rowsum[grow], rv);
    }
}

// ---------------- Kernel C: finalize ----------------
__global__ __launch_bounds__(256) void finalize_kernel(
    const float* __restrict__ rowsum, const float* __restrict__ pdot,
    float* __restrict__ out) {
    int t = threadIdx.x;
    const float4* rs4 = (const float4*)rowsum;
    const float4* pd4 = (const float4*)pdot;
    float s = 0.f, p = 0.f;
    for (int r = t; r < N2 / 4; r += 256) {
        float4 v = rs4[r];
        s += logf(v.x) + logf(v.y) + logf(v.z) + logf(v.w);
    }
    for (int r = t; r < NPAIR / 4; r += 256) {
        float4 v = pd4[r];
        p += v.x + v.y + v.z + v.w;
    }
    #pragma unroll
    for (int off = 32; off; off >>= 1) {
        s += __shfl_xor(s, off);
        p += __shfl_xor(p, off);
    }
    __shared__ float reds[4], redp[4];
    if ((t & 63) == 0) { reds[t >> 6] = s; redp[t >> 6] = p; }
    __syncthreads();
    if (t == 0) {
        float S = reds[0] + reds[1] + reds[2] + reds[3];
        float P = redp[0] + redp[1] + redp[2] + redp[3];
        // loss = (sum log D - (2/T)*2*sum(dp)) / 2N ; (2/T)*2 folded: 4*P
        out[0] = (S - 4.0f * P) / (float)N2;
    }
}

extern "C" void kernel_launch(void* const* d_in, const int* in_sizes, int n_in,
                              void* d_out, int out_size, void* d_ws, size_t ws_size,
                              hipStream_t stream) {
    const float* emb_i = (const float*)d_in[0];
    const float* emb_j = (const float*)d_in[1];
    float* out = (float*)d_out;

    char* ws = (char*)d_ws;
    float*          rowsum = (float*)ws;                    // 8192 * 4 B
    float*          pdot   = (float*)(ws + 32768);          // 4096 * 4 B
    unsigned short* reps   = (unsigned short*)(ws + 65536); // 8192*256*2 B

    normalize_kernel<<<NPAIR / 4, 256, 0, stream>>>(emb_i, emb_j, reps, pdot,
                                                    rowsum);

    simexp_kernel<<<NBLOCKS, 256, 0, stream>>>(reps, rowsum);

    finalize_kernel<<<1, 256, 0, stream>>>(rowsum, pdot, out);
}

// Round 6
// 52.720 us; speedup vs baseline: 2.2656x; 1.0455x over previous
//
#include <hip/hip_runtime.h>
#include <hip/hip_bf16.h>
#include <stdint.h>

#define NPAIR 4096
#define N2    8192      // 2N rows
#define DIM   256
#define BK    64
#define NK    (DIM / BK)   // 4 K-steps
#define NBLOCKS 2080       // 64*65/2 upper-triangle 128x128 blocks
// exp(x/T) = exp2(x * log2(e)/T), T=0.5
#define EXP_SCALE 2.8853900817779268f

typedef short bf16x8 __attribute__((ext_vector_type(8)));
typedef float f32x4  __attribute__((ext_vector_type(4)));

static __device__ __forceinline__ unsigned short f2bf(float f) {
    uint32_t u = __float_as_uint(f);
    uint32_t r = (u + 0x7fffu + ((u >> 16) & 1u)) >> 16;
    return (unsigned short)r;
}

static __device__ __forceinline__ void async_copy16(void* lds, const void* g) {
    __builtin_amdgcn_global_load_lds(
        (const __attribute__((address_space(1))) void*)g,
        (__attribute__((address_space(3))) void*)lds, 16, 0, 0);
}

// ---------------- Kernel A: normalize rows + positive dot + zero rowsum ----
__global__ __launch_bounds__(256) void normalize_kernel(
    const float* __restrict__ emb_i, const float* __restrict__ emb_j,
    unsigned short* __restrict__ reps, float* __restrict__ pdot,
    float* __restrict__ rowsum) {
    int i = blockIdx.x * 4 + (threadIdx.x >> 6);
    int l = threadIdx.x & 63;       // 0..63, 4 floats each
    float4 a = ((const float4*)(emb_i + (size_t)i * DIM))[l];
    float4 b = ((const float4*)(emb_j + (size_t)i * DIM))[l];
    float si = a.x*a.x + a.y*a.y + a.z*a.z + a.w*a.w;
    float sj = b.x*b.x + b.y*b.y + b.z*b.z + b.w*b.w;
    float dp = a.x*b.x + a.y*b.y + a.z*b.z + a.w*b.w;
    #pragma unroll
    for (int off = 32; off; off >>= 1) {
        si += __shfl_xor(si, off);
        sj += __shfl_xor(sj, off);
        dp += __shfl_xor(dp, off);
    }
    float ri = 1.0f / fmaxf(sqrtf(si), 1e-12f);
    float rj = 1.0f / fmaxf(sqrtf(sj), 1e-12f);

    ushort4 ua, ub;
    ua.x = f2bf(a.x * ri); ua.y = f2bf(a.y * ri);
    ua.z = f2bf(a.z * ri); ua.w = f2bf(a.w * ri);
    ub.x = f2bf(b.x * rj); ub.y = f2bf(b.y * rj);
    ub.z = f2bf(b.z * rj); ub.w = f2bf(b.w * rj);
    *(ushort4*)(reps + (size_t)i * DIM + l * 4)            = ua;
    *(ushort4*)(reps + (size_t)(i + NPAIR) * DIM + l * 4)  = ub;

    if (l == 0) pdot[i] = dp * ri * rj;
    if (l < 2)  rowsum[2 * i + l] = 0.f;
}

// ---------- Kernel B: upper-triangle sim blocks + exp + partial sums -------
// Triangle is walked in ANTI-DIAGONAL order: diagonal d holds blocks
// (i, i+d), so concurrently-resident blocks have pairwise-distinct bI and
// bJ -> disjoint rowsum atomic targets (kills the same-bJ line contention
// of the row-major triangle walk). Per block, the 2x duplicated wave
// partials are combined through LDS (aliased onto dead As[0]) so only 256
// atomics/block are issued, by distinct waves.
// Inner loop unchanged from r5: 128x128 tile, 4 waves, 16x16x32 bf16 MFMA,
// BK=64, both-sides XOR swizzle, double-buffered LDS with 1-deep prefetch.
__global__ __launch_bounds__(256) void simexp_kernel(
    const unsigned short* __restrict__ reps, float* __restrict__ rowsum) {
    __shared__ unsigned short As[2][128 * BK];
    __shared__ unsigned short Bs[2][128 * BK];

    int t = threadIdx.x;
    int l = t & 63;
    int w = t >> 6;
    int wr = w >> 1, wc = w & 1;

    // anti-diagonal decode: C(d) = d*(129-d)/2 blocks before diagonal d
    int idx = blockIdx.x;
    int d = (int)((129.0f - sqrtf(129.0f * 129.0f - 8.0f * (float)idx)) * 0.5f);
    while (d * (129 - d) / 2 > idx) --d;
    while ((d + 1) * (128 - d) / 2 <= idx) ++d;
    int i0 = idx - d * (129 - d) / 2;
    int bI = i0, bJ = i0 + d;
    int brow = bI * 128;
    int bcol = bJ * 128;
    bool diag = (d == 0);

    f32x4 acc[4][4];
    #pragma unroll
    for (int mi = 0; mi < 4; ++mi)
        #pragma unroll
        for (int ni = 0; ni < 4; ++ni)
            acc[mi][ni] = (f32x4){0.f, 0.f, 0.f, 0.f};

    int frow = l & 15;
    int k16  = l >> 4;          // 0..3

    // staging addresses (per-thread constants across K-steps)
    int f16r  = t >> 3;                 // tile row for my 16B chunk
    int slot0 = t & 7;                  // slot within 128B row
    int gk0   = (slot0 ^ (f16r & 7)) * 8;   // pre-swizzled k-chunk (elements)

    #define STAGE(buf, kt)                                                     \
        _Pragma("unroll")                                                      \
        for (int p = 0; p < 4; ++p) {                                          \
            int r = f16r + p * 32;                                             \
            async_copy16(&As[buf][(t + p * 256) * 8],                          \
                         reps + (size_t)(brow + r) * DIM + (kt) * BK + gk0);   \
            async_copy16(&Bs[buf][(t + p * 256) * 8],                          \
                         reps + (size_t)(bcol + r) * DIM + (kt) * BK + gk0);   \
        }

    STAGE(0, 0);
    asm volatile("s_waitcnt vmcnt(0)" ::: "memory");
    __syncthreads();

    #pragma unroll
    for (int kt = 0; kt < NK; ++kt) {
        const int cur = kt & 1;
        if (kt < NK - 1) { STAGE(cur ^ 1, kt + 1); }   // prefetch next K-tile

        #pragma unroll
        for (int kk = 0; kk < 2; ++kk) {
            bf16x8 afr[4], bfr[4];
            #pragma unroll
            for (int ni = 0; ni < 4; ++ni) {
                int r    = wc * 64 + ni * 16 + frow;
                int slot = (kk * 4 + k16) ^ (r & 7);
                bfr[ni] = *(const bf16x8*)&Bs[cur][r * BK + slot * 8];
            }
            #pragma unroll
            for (int mi = 0; mi < 4; ++mi) {
                int r    = wr * 64 + mi * 16 + frow;
                int slot = (kk * 4 + k16) ^ (r & 7);
                afr[mi] = *(const bf16x8*)&As[cur][r * BK + slot * 8];
            }
            #pragma unroll
            for (int mi = 0; mi < 4; ++mi)
                #pragma unroll
                for (int ni = 0; ni < 4; ++ni)
                    acc[mi][ni] = __builtin_amdgcn_mfma_f32_16x16x32_bf16(
                        afr[mi], bfr[ni], acc[mi][ni], 0, 0, 0);
        }

        if (kt < NK - 1) {
            asm volatile("s_waitcnt vmcnt(0)" ::: "memory");  // next tile landed
            __syncthreads();   // also separates reads(cur) from next STAGE(cur)
        }
    }
    #undef STAGE

    // Epilogue. C/D layout: col = lane&15, row = (lane>>4)*4 + j  [m89/m91]
    int rbase = brow + wr * 64 + k16 * 4;
    int cb    = bcol + wc * 64 + frow;
    float csum[4] = {0.f, 0.f, 0.f, 0.f};
    float rv = 0.f;
    #pragma unroll
    for (int mi = 0; mi < 4; ++mi) {
        #pragma unroll
        for (int j = 0; j < 4; ++j) {
            int grow = rbase + mi * 16 + j;
            float rp = 0.f;
            #pragma unroll
            for (int ni = 0; ni < 4; ++ni) {
                float e = exp2f(acc[mi][ni][j] * EXP_SCALE);
                e = (grow == cb + ni * 16) ? 0.f : e;   // main diagonal only
                csum[ni] += e;
                rp += e;
            }
            rp += __shfl_xor(rp, 1);
            rp += __shfl_xor(rp, 2);
            rp += __shfl_xor(rp, 4);
            rp += __shfl_xor(rp, 8);
            rv = (frow == mi * 4 + j) ? rp : rv;
        }
    }
    // column totals within wave: reduce over k16 groups
    #pragma unroll
    for (int ni = 0; ni < 4; ++ni) {
        csum[ni] += __shfl_xor(csum[ni], 16);
        csum[ni] += __shfl_xor(csum[ni], 32);
    }
    float cv = csum[0];
    #pragma unroll
    for (int v = 1; v < 4; ++v) cv = (k16 == v) ? csum[v] : cv;  // static idx

    // cross-wave combine through LDS aliased onto dead As[0]
    // (all reads of As finished: kt=2's trailing barrier covers As[0];
    //  kt=3 reads As[1]/Bs[1] only, and red aliases As[0])
    float* red = (float*)&As[0][0];     // [0..255]=cred, [256..511]=rred
    red[w * 64 + l] = cv;               // col partial: col = bcol+(w&1)*64+l
    int roff = k16 * 4 + (frow >> 2) * 16 + (frow & 3);  // bijection on 0..63
    red[256 + w * 64 + roff] = rv;      // row partial: row = brow+(w>>1)*64+roff
    __syncthreads();

    if (w < 2) {        // waves 0,1: finalize 128 column atomics
        float v = red[w * 64 + l] + red[(w + 2) * 64 + l];
        atomicAdd(&rowsum[bcol + w * 64 + l], v);
    } else if (!diag) { // waves 2,3: finalize 128 row atomics
        int half = w - 2;
        float v = red[256 + (2 * half) * 64 + l] + red[256 + (2 * half + 1) * 64 + l];
        atomicAdd(&rowsum[brow + half * 64 + l], v);
    }
}

// ---------------- Kernel C: finalize ----------------
__global__ __launch_bounds__(256) void finalize_kernel(
    const float* __restrict__ rowsum, const float* __restrict__ pdot,
    float* __restrict__ out) {
    int t = threadIdx.x;
    const float4* rs4 = (const float4*)rowsum;
    const float4* pd4 = (const float4*)pdot;
    float s = 0.f, p = 0.f;
    for (int r = t; r < N2 / 4; r += 256) {
        float4 v = rs4[r];
        s += logf(v.x) + logf(v.y) + logf(v.z) + logf(v.w);
    }
    for (int r = t; r < NPAIR / 4; r += 256) {
        float4 v = pd4[r];
        p += v.x + v.y + v.z + v.w;
    }
    #pragma unroll
    for (int off = 32; off; off >>= 1) {
        s += __shfl_xor(s, off);
        p += __shfl_xor(p, off);
    }
    __shared__ float reds[4], redp[4];
    if ((t & 63) == 0) { reds[t >> 6] = s; redp[t >> 6] = p; }
    __syncthreads();
    if (t == 0) {
        float S = reds[0] + reds[1] + reds[2] + reds[3];
        float P = redp[0] + redp[1] + redp[2] + redp[3];
        // loss = (sum log D - (2/T)*2*sum(dp)) / 2N ; (2/T)*2 folded: 4*P
        out[0] = (S - 4.0f * P) / (float)N2;
    }
}

extern "C" void kernel_launch(void* const* d_in, const int* in_sizes, int n_in,
                              void* d_out, int out_size, void* d_ws, size_t ws_size,
                              hipStream_t stream) {
    const float* emb_i = (const float*)d_in[0];
    const float* emb_j = (const float*)d_in[1];
    float* out = (float*)d_out;

    char* ws = (char*)d_ws;
    float*          rowsum = (float*)ws;                    // 8192 * 4 B
    float*          pdot   = (float*)(ws + 32768);          // 4096 * 4 B
    unsigned short* reps   = (unsigned short*)(ws + 65536); // 8192*256*2 B

    normalize_kernel<<<NPAIR / 4, 256, 0, stream>>>(emb_i, emb_j, reps, pdot,
                                                    rowsum);

    simexp_kernel<<<NBLOCKS, 256, 0, stream>>>(reps, rowsum);

    finalize_kernel<<<1, 256, 0, stream>>>(rowsum, pdot, out);
}